// Round 19
// baseline (188.689 us; speedup 1.0000x reference)
//
#include <hip/hip_runtime.h>

#define EPS 1e-10f
#define HALF_LN2PI 0.91893853320467274f
#define LOG2E 1.4426950408889634f

// b=16, win=14, w=6, ww=36, B_T=32, K=3, Bkk=288 (=i), C_T=32, HH=16
// W flat: [i=288][c=32][hr=4][m=4]
// Pt per (bb,p) (natural layout): Pt[i*16 + e] = patchflat[base(p)+e],
//   e = m*4+hc, base(p)=(p/6)*96+(p%6)*16.
//
// Grid (m/e): 2304 blocks = (blk = bb*36+p)*4 + iq, 192 threads = 3 waves.
// Wave handles 24 i. 9 blocks/CU x 3 waves = 27 waves/CU. VGPR must stay <=64.
// lane = cl*4+hr; thread covers c in {cl, cl+16}, 4 hc each.
// Mpart[bid][k*64+lane], k: [0..3]=S1a [4..7]=S2a [8..11]=S1b [12..15]=S2b [16]=sRa [17]=sRb
//
// Structure: m0 -> e0 -> m1 -> e1 -> m2 -> out (6 dispatches).
//
// Post-mortems: r6 coop grid.sync = L2 flush; r7 full-unroll spill; r8 no
// global VMEM in t-loops; r9 no memset, DPP reduce; r10 stats in registers;
// r11/r12 output path FREE; r13 exp swap = 20us/pass; r14/r15 scalar instr
// cuts null; r16 3 waves (+50% occupancy) worked; r17/r18 packed FP32 cut
// VALUBusy 70->54 but NOT time -> not VALU-issue-bound. r19 (this): last
// standing theory = v_exp_f32 trans pipe is a serialized shared resource;
// replace with packed polynomial exp2 (deg-5 minimax, ~7 VALU ops/exp) to
// move the work onto the VALU pipe which has 46% headroom.

typedef float f32x2 __attribute__((ext_vector_type(2)));

__device__ __forceinline__ f32x2 fma2(f32x2 a, f32x2 b, f32x2 c) {
    return __builtin_elementwise_fma(a, b, c);
}
__device__ __forceinline__ f32x2 sp2(float x) { return f32x2{x, x}; }

// packed polynomial 2^x (x clamped to >= -126; handles x up to ~+60).
// deg-5 minimax for 2^f on [0,1), rel err ~2e-8; scale by 2^n via bit add.
__device__ __forceinline__ f32x2 fast_exp2(f32x2 x) {
    x.x = fmaxf(x.x, -126.0f);
    x.y = fmaxf(x.y, -126.0f);
    const float n0f = floorf(x.x), n1f = floorf(x.y);
    const f32x2 f = x - f32x2{n0f, n1f};
    f32x2 p = sp2(1.8775767e-3f);
    p = fma2(p, f, sp2(8.9893397e-3f));
    p = fma2(p, f, sp2(5.5826318e-2f));
    p = fma2(p, f, sp2(2.4015361e-1f));
    p = fma2(p, f, sp2(6.9315308e-1f));
    p = fma2(p, f, sp2(1.0f));
    const int b0 = __float_as_int(p.x) + ((int)n0f << 23);
    const int b1 = __float_as_int(p.y) + ((int)n1f << 23);
    return f32x2{__int_as_float(b0), __int_as_float(b1)};
}

// packed dot-product pair for one c: out01 = {V(hc0),V(hc1)}, out23 = {V(hc2),V(hc3)}
__device__ __forceinline__ void dot_pairs(const float4 wv,
                                          const float4 q0, const float4 q1,
                                          const float4 q2, const float4 q3,
                                          f32x2& out01, f32x2& out23)
{
    out01 = fma2(sp2(wv.x), f32x2{q0.x, q0.y},
            fma2(sp2(wv.y), f32x2{q1.x, q1.y},
            fma2(sp2(wv.z), f32x2{q2.x, q2.y}, sp2(wv.w) * f32x2{q3.x, q3.y})));
    out23 = fma2(sp2(wv.x), f32x2{q0.z, q0.w},
            fma2(sp2(wv.y), f32x2{q1.z, q1.w},
            fma2(sp2(wv.z), f32x2{q2.z, q2.w}, sp2(wv.w) * f32x2{q3.z, q3.w})));
}

// quad-level XOR butterfly adds via DPP (single VALU op each, no LDS pipe)
__device__ __forceinline__ float qxor1_add(float x) {
    float r;
    asm("v_add_f32 %0, %1, %1 quad_perm:[1,0,3,2] row_mask:0xf bank_mask:0xf"
        : "=v"(r) : "v"(x));
    return r;
}
__device__ __forceinline__ float qxor2_add(float x) {
    float r;
    asm("v_add_f32 %0, %1, %1 quad_perm:[2,3,0,1] row_mask:0xf bank_mask:0xf"
        : "=v"(r) : "v"(x));
    return r;
}

template <int IT>
__global__ __launch_bounds__(192)
void m_pass(const float* __restrict__ poses, const float* __restrict__ acts,
            float* __restrict__ Ptg, float* __restrict__ actp,
            const float* __restrict__ W,
            const float* __restrict__ ap_buf, const float* __restrict__ denom_prev,
            float* __restrict__ Mpart, float* __restrict__ denom_zero)
{
    __shared__ __align__(16) float Pt_lds[1152];
    __shared__ float act_lds[72];
    __shared__ float invd_lds[72];
    __shared__ __align__(16) float red[2304];   // 2 donor waves x 64 x 18

    const int tid  = threadIdx.x;
    const int wave = tid / 64, lane = tid & 63;
    const int cl   = lane >> 2;
    const int bid  = blockIdx.x;
    const int blk  = bid >> 2, iq = bid & 3;
    const int bb   = blk / 36, p = blk - bb * 36;
    const int i0   = iq * 72;
    const int iw   = i0 + wave * 24;
    const size_t pbase  = (size_t)blk * 4608;
    const size_t apbase = (size_t)blk * 9216;

    if (tid < 72)
        denom_zero[bb * 288 + i0 + tid] = 0.0f;

    if (IT == 0) {
        const int base = (p / 6) * 96 + (p % 6) * 16;
        for (int e = tid; e < 1152; e += 192) {
            int il = e >> 4, j = e & 15;
            int i = i0 + il;
            int f = base + j;                   // natural layout
            int h = f / 36, sp = f - h * 36;
            int y = sp / 6, x = sp - y * 6;
            int B = i / 9, kk = i - B * 9;
            int ki = kk / 3, kj = kk - ki * 3;
            float v = poses[(size_t)((bb * 512 + h * 32 + B) * 14 + 2 * x + ki) * 14 + 2 * y + kj];
            Pt_lds[e] = v;
            Ptg[pbase + (size_t)i0 * 16 + e] = v;
        }
        const int y = p / 6, x = p - y * 6;
        for (int e = tid; e < 72; e += 192) {
            int i = i0 + e;
            int B = i / 9, kk = i - B * 9;
            int ki = kk / 3, kj = kk - ki * 3;
            float v = acts[(size_t)((bb * 32 + B) * 14 + 2 * x + ki) * 14 + 2 * y + kj];
            act_lds[e] = v;
            actp[blk * 288 + i] = v;
        }
    } else {
        const float4* src = (const float4*)(Ptg + pbase + (size_t)i0 * 16);
        float4* dst = (float4*)Pt_lds;
        for (int e = tid; e < 288; e += 192) dst[e] = src[e];
        for (int e = tid; e < 72; e += 192) {
            act_lds[e]  = actp[blk * 288 + i0 + e];
            invd_lds[e] = 1.0f / (denom_prev[bb * 288 + i0 + e] + EPS);
        }
    }
    __syncthreads();

    f32x2 s1a01 = {0,0}, s1a23 = {0,0}, s2a01 = {0,0}, s2a23 = {0,0};
    f32x2 s1b01 = {0,0}, s1b23 = {0,0}, s2b01 = {0,0}, s2b23 = {0,0};
    float sRa = 0.f, sRb = 0.f;

    const float* Wt  = W + (size_t)iw * 512 + (lane << 2);
    const float* apc = ap_buf + apbase + (size_t)iw * 32 + cl;

#pragma unroll 6
    for (int t = 0; t < 24; ++t) {
        const int il = wave * 24 + t;
        const float4 wva = *(const float4*)(Wt + (size_t)t * 512);
        const float4 wvb = *(const float4*)(Wt + (size_t)t * 512 + 256);
        float Ra, Rb;
        if (IT == 0) {
            Ra = 1.0f / 32.0f; Rb = 1.0f / 32.0f;
        } else {
            const float inv = invd_lds[il];
            Ra = fmaf(apc[(size_t)t * 32],      inv, EPS);
            Rb = fmaf(apc[(size_t)t * 32 + 16], inv, EPS);
        }
        const float a_in = act_lds[il];
        const float R4a = Ra * a_in, R4b = Rb * a_in;
        sRa += R4a; sRb += R4b;

        const float4 q0 = *(const float4*)&Pt_lds[il * 16 + 0];
        const float4 q1 = *(const float4*)&Pt_lds[il * 16 + 4];
        const float4 q2 = *(const float4*)&Pt_lds[il * 16 + 8];
        const float4 q3 = *(const float4*)&Pt_lds[il * 16 + 12];

        f32x2 va01, va23, vb01, vb23;
        dot_pairs(wva, q0, q1, q2, q3, va01, va23);
        dot_pairs(wvb, q0, q1, q2, q3, vb01, vb23);

        const f32x2 ra2 = sp2(R4a), rb2 = sp2(R4b);
        s1a01 = fma2(ra2, va01, s1a01);
        s1a23 = fma2(ra2, va23, s1a23);
        s1b01 = fma2(rb2, vb01, s1b01);
        s1b23 = fma2(rb2, vb23, s1b23);
        const f32x2 ua01 = ra2 * va01, ua23 = ra2 * va23;
        const f32x2 ub01 = rb2 * vb01, ub23 = rb2 * vb23;
        s2a01 = fma2(ua01, va01, s2a01);
        s2a23 = fma2(ua23, va23, s2a23);
        s2b01 = fma2(ub01, vb01, s2b01);
        s2b23 = fma2(ub23, vb23, s2b23);
    }

    float acc[18] = {
        s1a01.x, s1a01.y, s1a23.x, s1a23.y,
        s2a01.x, s2a01.y, s2a23.x, s2a23.y,
        s1b01.x, s1b01.y, s1b23.x, s1b23.y,
        s2b01.x, s2b01.y, s2b23.x, s2b23.y,
        sRa, sRb
    };

    if (wave > 0) {
        float* d = &red[((wave - 1) * 64 + lane) * 18];
#pragma unroll
        for (int k = 0; k < 18; ++k) d[k] = acc[k];
    }
    __syncthreads();
    if (wave == 0) {
        float* mp = Mpart + (size_t)bid * 1152;
        const float* r0 = &red[lane * 18];
        const float* r1 = &red[(64 + lane) * 18];
#pragma unroll
        for (int k = 0; k < 18; ++k)
            mp[k * 64 + lane] = acc[k] + r0[k] + r1[k];
    }
}

__global__ __launch_bounds__(192)
void e_pass(const float* __restrict__ Ptg, const float* __restrict__ Mpart,
            const float* __restrict__ W, const float* __restrict__ beta_v,
            const float* __restrict__ beta_a, const float* __restrict__ lambda_p,
            float* __restrict__ ap_buf, float* __restrict__ denom_next)
{
    __shared__ __align__(16) float Pt_lds[1152];
    __shared__ __align__(16) float ap_lds[2304];

    const int tid  = threadIdx.x;
    const int wave = tid / 64, lane = tid & 63;
    const int cl   = lane >> 2, hr = lane & 3;
    const int bid  = blockIdx.x;
    const int blk  = bid >> 2, iq = bid & 3;
    const int bb   = blk / 36;
    const int i0   = iq * 72;
    const int iw   = i0 + wave * 24;
    const size_t pbase  = (size_t)blk * 4608;
    const size_t apbase = (size_t)blk * 9216;

    {
        const float4* src = (const float4*)(Ptg + pbase + (size_t)i0 * 16);
        float4* dst = (float4*)Pt_lds;
        for (int e = tid; e < 288; e += 192) dst[e] = src[e];
    }

    // ---- stats in registers; Horner coeffs packed as hc-pairs ----
    f32x2 cA2a[2], cA1a[2], cA0a[2], cA2b[2], cA1b[2], cA0b[2];
    float aca, acb;
    {
        const float* mp = Mpart + (size_t)blk * 4608;
        float s[18];
#pragma unroll
        for (int k = 0; k < 18; ++k)
            s[k] = mp[k * 64 + lane] + mp[1152 + k * 64 + lane]
                 + mp[2304 + k * 64 + lane] + mp[3456 + k * 64 + lane];
        const float lam = lambda_p[0];
        float A2s[8], A1s[8], A0s[8];
#pragma unroll
        for (int q = 0; q < 2; ++q) {
            const int c = cl + q * 16;
            const float sR = s[16 + q];
            float ls = 0.f;
#pragma unroll
            for (int hc = 0; hc < 4; ++hc) {
                const float mu = s[q * 8 + hc] / sR;
                float ss = s[q * 8 + 4 + hc] / sR - mu * mu;
                ss = fmaxf(ss, 1e-30f);
                const float n2 = (-0.5f / ss) * LOG2E;
                const float hl = (-0.5f * __logf(ss) - HALF_LN2PI) * LOG2E;
                A2s[q * 4 + hc] = n2;
                A1s[q * 4 + hc] = -2.0f * n2 * mu;
                A0s[q * 4 + hc] = fmaf(n2 * mu, mu, hl);
                ls += __logf(sqrtf(ss) + EPS);
            }
            ls += __shfl_xor(ls, 1);
            ls += __shfl_xor(ls, 2);
            const float cost = sR * (16.0f * beta_v[c] + ls);
            const float av = 1.0f / (1.0f + __expf(-lam * (beta_a[c] - cost)));
            if (q) acb = av; else aca = av;
        }
        cA2a[0] = f32x2{A2s[0], A2s[1]}; cA2a[1] = f32x2{A2s[2], A2s[3]};
        cA1a[0] = f32x2{A1s[0], A1s[1]}; cA1a[1] = f32x2{A1s[2], A1s[3]};
        cA0a[0] = f32x2{A0s[0], A0s[1]}; cA0a[1] = f32x2{A0s[2], A0s[3]};
        cA2b[0] = f32x2{A2s[4], A2s[5]}; cA2b[1] = f32x2{A2s[6], A2s[7]};
        cA1b[0] = f32x2{A1s[4], A1s[5]}; cA1b[1] = f32x2{A1s[6], A1s[7]};
        cA0b[0] = f32x2{A0s[4], A0s[5]}; cA0b[1] = f32x2{A0s[6], A0s[7]};
    }
    __syncthreads();

    const float* Wt = W + (size_t)iw * 512 + (lane << 2);

    // ---- t-loop: packed dots + packed Horner + PACKED POLY EXP2 (r19) ----
#pragma unroll 6
    for (int t = 0; t < 24; ++t) {
        const int il = wave * 24 + t;
        const float4 wva = *(const float4*)(Wt + (size_t)t * 512);
        const float4 wvb = *(const float4*)(Wt + (size_t)t * 512 + 256);

        const float4 q0 = *(const float4*)&Pt_lds[il * 16 + 0];
        const float4 q1 = *(const float4*)&Pt_lds[il * 16 + 4];
        const float4 q2 = *(const float4*)&Pt_lds[il * 16 + 8];
        const float4 q3 = *(const float4*)&Pt_lds[il * 16 + 12];

        f32x2 va01, va23, vb01, vb23;
        dot_pairs(wva, q0, q1, q2, q3, va01, va23);
        dot_pairs(wvb, q0, q1, q2, q3, vb01, vb23);

        const f32x2 ga01 = fma2(va01, fma2(va01, cA2a[0], cA1a[0]), cA0a[0]);
        const f32x2 ga23 = fma2(va23, fma2(va23, cA2a[1], cA1a[1]), cA0a[1]);
        const f32x2 gb01 = fma2(vb01, fma2(vb01, cA2b[0], cA1b[0]), cA0b[0]);
        const f32x2 gb23 = fma2(vb23, fma2(vb23, cA2b[1], cA1b[1]), cA0b[1]);

        const f32x2 sa = fast_exp2(ga01) + fast_exp2(ga23);
        const f32x2 sb = fast_exp2(gb01) + fast_exp2(gb23);
        float pea = sa.x + sa.y;
        float peb = sb.x + sb.y;

        pea = qxor1_add(pea); pea = qxor2_add(pea);
        peb = qxor1_add(peb); peb = qxor2_add(peb);
        if (hr == 0) {
            ap_lds[il * 32 + cl]      = aca * pea;
            ap_lds[il * 32 + cl + 16] = acb * peb;
        }
    }
    __syncthreads();

    {
        const float4* s4 = (const float4*)ap_lds;
        float4* d4 = (float4*)(ap_buf + apbase + (size_t)i0 * 32);
        for (int e = tid; e < 576; e += 192) d4[e] = s4[e];
    }
    if (tid < 72) {
        float s = 0.f;
#pragma unroll
        for (int c = 0; c < 32; ++c)
            s += ap_lds[tid * 32 + ((c + tid) & 31)];
        atomicAdd(&denom_next[bb * 288 + i0 + tid], s);
    }
}

__global__ __launch_bounds__(64)
void out_pass(const float* __restrict__ Mpart, const float* __restrict__ beta_v,
              const float* __restrict__ beta_a, const float* __restrict__ lambda_p,
              float* __restrict__ d_out)
{
    const int lane = threadIdx.x;
    const int cl = lane >> 2, hr = lane & 3;
    const int blk = blockIdx.x;
    const int bb = blk / 36, p = blk - bb * 36;
    const float* mp = Mpart + (size_t)blk * 4608;

    float s[18];
#pragma unroll
    for (int k = 0; k < 18; ++k)
        s[k] = mp[k * 64 + lane] + mp[1152 + k * 64 + lane]
             + mp[2304 + k * 64 + lane] + mp[3456 + k * 64 + lane];

    const float lam = lambda_p[0];
#pragma unroll
    for (int q = 0; q < 2; ++q) {
        const int c = cl + q * 16;
        const float sR = s[16 + q];
        float ls = 0.f;
#pragma unroll
        for (int hc = 0; hc < 4; ++hc) {
            const float mu = s[q * 8 + hc] / sR;
            float ss = s[q * 8 + 4 + hc] / sR - mu * mu;
            ss = fmaxf(ss, 1e-30f);
            d_out[(size_t)bb * 18432 + (size_t)(c * 36 + p) * 16 + hr * 4 + hc] = mu;
            ls += __logf(sqrtf(ss) + EPS);
        }
        ls += __shfl_xor(ls, 1);
        ls += __shfl_xor(ls, 2);
        const float cost = sR * (16.0f * beta_v[c] + ls);
        const float av = 1.0f / (1.0f + __expf(-lam * (beta_a[c] - cost)));
        if (hr == 0)
            d_out[294912 + (size_t)bb * 1152 + c * 36 + p] = av;
    }
}

extern "C" void kernel_launch(void* const* d_in, const int* in_sizes, int n_in,
                              void* d_out, int out_size, void* d_ws, size_t ws_size,
                              hipStream_t stream)
{
    const float* lambda_p = (const float*)d_in[0];
    const float* poses    = (const float*)d_in[1];
    const float* acts     = (const float*)d_in[2];
    const float* W        = (const float*)d_in[3];
    const float* beta_v   = (const float*)d_in[4];
    const float* beta_a   = (const float*)d_in[5];
    float* out = (float*)d_out;

    float* ws     = (float*)d_ws;
    float* Ptg    = ws;                     // 576*4608 = 2,654,208 floats
    float* actp   = Ptg + 2654208;          // 576*288  =   165,888
    float* ap_buf = actp + 165888;          // 576*9216 = 5,308,416
    float* Mpart  = ap_buf + 5308416;       // 2304*1152 = 2,654,208
    float* denom0 = Mpart + 2654208;        // 4608
    float* denom1 = denom0 + 4608;          // 4608

    m_pass<0><<<2304, 192, 0, stream>>>(poses, acts, Ptg, actp, W, ap_buf, denom1, Mpart, denom0);
    e_pass<<<2304, 192, 0, stream>>>(Ptg, Mpart, W, beta_v, beta_a, lambda_p, ap_buf, denom0);
    m_pass<1><<<2304, 192, 0, stream>>>(poses, acts, Ptg, actp, W, ap_buf, denom0, Mpart, denom1);
    e_pass<<<2304, 192, 0, stream>>>(Ptg, Mpart, W, beta_v, beta_a, lambda_p, ap_buf, denom1);
    m_pass<1><<<2304, 192, 0, stream>>>(poses, acts, Ptg, actp, W, ap_buf, denom1, Mpart, denom0);
    out_pass<<<576, 64, 0, stream>>>(Mpart, beta_v, beta_a, lambda_p, out);
}

// Round 20
// 163.084 us; speedup vs baseline: 1.1570x; 1.1570x over previous
//
#include <hip/hip_runtime.h>

#define EPS 1e-10f
#define HALF_LN2PI 0.91893853320467274f
#define LOG2E 1.4426950408889634f

// b=16, win=14, w=6, ww=36, B_T=32, K=3, Bkk=288 (=i), C_T=32, HH=16
// W flat: [i=288][c=32][hr=4][m=4]
// Pt per (bb,p) (natural layout): Pt[i*16 + e] = patchflat[base(p)+e],
//   e = m*4+hc, base(p)=(p/6)*96+(p%6)*16.
//
// Grid (m/e): 2304 blocks = (blk = bb*36+p)*4 + iq, 192 threads = 3 waves.
// Wave handles 24 i. 9 blocks/CU x 3 waves = 27 waves/CU. VGPR must stay <=64.
// lane = cl*4+hr; thread covers c in {cl, cl+16}, 4 hc each.
// Mpart[bid][k*64+lane], k: [0..3]=S1a [4..7]=S2a [8..11]=S1b [12..15]=S2b [16]=sRa [17]=sRb
//
// Structure: m0 -> e0 -> m1 -> e1 -> m2 -> out (6 dispatches).
//
// Post-mortems: r6 coop grid.sync = L2 flush; r7 full-unroll spill; r8 no
// global VMEM in t-loops; r9 no memset, DPP reduce; r10 stats in registers;
// r11/r12 output path FREE; r13 exp-delta = dependency not throughput;
// r14/r15 scalar instr cuts null; r16 3 waves (+50% occupancy) +7us;
// r17/r18 packed FP32 cut VALUBusy 70->54, time flat -> not issue-bound;
// r19 poly-exp HURT (+13us) -> trans pipe was fine; falsified.
// r20 (this): revert to r18 (best, 163us); sole change = e t-loop unroll
// 6->8 (more in-flight W loads). Null -> structure at practical floor.

typedef float f32x2 __attribute__((ext_vector_type(2)));

__device__ __forceinline__ f32x2 fma2(f32x2 a, f32x2 b, f32x2 c) {
    return __builtin_elementwise_fma(a, b, c);
}
__device__ __forceinline__ f32x2 sp2(float x) { return f32x2{x, x}; }

// packed dot-product pair for one c: out01 = {V(hc0),V(hc1)}, out23 = {V(hc2),V(hc3)}
__device__ __forceinline__ void dot_pairs(const float4 wv,
                                          const float4 q0, const float4 q1,
                                          const float4 q2, const float4 q3,
                                          f32x2& out01, f32x2& out23)
{
    out01 = fma2(sp2(wv.x), f32x2{q0.x, q0.y},
            fma2(sp2(wv.y), f32x2{q1.x, q1.y},
            fma2(sp2(wv.z), f32x2{q2.x, q2.y}, sp2(wv.w) * f32x2{q3.x, q3.y})));
    out23 = fma2(sp2(wv.x), f32x2{q0.z, q0.w},
            fma2(sp2(wv.y), f32x2{q1.z, q1.w},
            fma2(sp2(wv.z), f32x2{q2.z, q2.w}, sp2(wv.w) * f32x2{q3.z, q3.w})));
}

// quad-level XOR butterfly adds via DPP (single VALU op each, no LDS pipe)
__device__ __forceinline__ float qxor1_add(float x) {
    float r;
    asm("v_add_f32 %0, %1, %1 quad_perm:[1,0,3,2] row_mask:0xf bank_mask:0xf"
        : "=v"(r) : "v"(x));
    return r;
}
__device__ __forceinline__ float qxor2_add(float x) {
    float r;
    asm("v_add_f32 %0, %1, %1 quad_perm:[2,3,0,1] row_mask:0xf bank_mask:0xf"
        : "=v"(r) : "v"(x));
    return r;
}

template <int IT>
__global__ __launch_bounds__(192)
void m_pass(const float* __restrict__ poses, const float* __restrict__ acts,
            float* __restrict__ Ptg, float* __restrict__ actp,
            const float* __restrict__ W,
            const float* __restrict__ ap_buf, const float* __restrict__ denom_prev,
            float* __restrict__ Mpart, float* __restrict__ denom_zero)
{
    __shared__ __align__(16) float Pt_lds[1152];
    __shared__ float act_lds[72];
    __shared__ float invd_lds[72];
    __shared__ __align__(16) float red[2304];   // 2 donor waves x 64 x 18

    const int tid  = threadIdx.x;
    const int wave = tid / 64, lane = tid & 63;
    const int cl   = lane >> 2;
    const int bid  = blockIdx.x;
    const int blk  = bid >> 2, iq = bid & 3;
    const int bb   = blk / 36, p = blk - bb * 36;
    const int i0   = iq * 72;
    const int iw   = i0 + wave * 24;
    const size_t pbase  = (size_t)blk * 4608;
    const size_t apbase = (size_t)blk * 9216;

    if (tid < 72)
        denom_zero[bb * 288 + i0 + tid] = 0.0f;

    if (IT == 0) {
        const int base = (p / 6) * 96 + (p % 6) * 16;
        for (int e = tid; e < 1152; e += 192) {
            int il = e >> 4, j = e & 15;
            int i = i0 + il;
            int f = base + j;                   // natural layout
            int h = f / 36, sp = f - h * 36;
            int y = sp / 6, x = sp - y * 6;
            int B = i / 9, kk = i - B * 9;
            int ki = kk / 3, kj = kk - ki * 3;
            float v = poses[(size_t)((bb * 512 + h * 32 + B) * 14 + 2 * x + ki) * 14 + 2 * y + kj];
            Pt_lds[e] = v;
            Ptg[pbase + (size_t)i0 * 16 + e] = v;
        }
        const int y = p / 6, x = p - y * 6;
        for (int e = tid; e < 72; e += 192) {
            int i = i0 + e;
            int B = i / 9, kk = i - B * 9;
            int ki = kk / 3, kj = kk - ki * 3;
            float v = acts[(size_t)((bb * 32 + B) * 14 + 2 * x + ki) * 14 + 2 * y + kj];
            act_lds[e] = v;
            actp[blk * 288 + i] = v;
        }
    } else {
        const float4* src = (const float4*)(Ptg + pbase + (size_t)i0 * 16);
        float4* dst = (float4*)Pt_lds;
        for (int e = tid; e < 288; e += 192) dst[e] = src[e];
        for (int e = tid; e < 72; e += 192) {
            act_lds[e]  = actp[blk * 288 + i0 + e];
            invd_lds[e] = 1.0f / (denom_prev[bb * 288 + i0 + e] + EPS);
        }
    }
    __syncthreads();

    f32x2 s1a01 = {0,0}, s1a23 = {0,0}, s2a01 = {0,0}, s2a23 = {0,0};
    f32x2 s1b01 = {0,0}, s1b23 = {0,0}, s2b01 = {0,0}, s2b23 = {0,0};
    float sRa = 0.f, sRb = 0.f;

    const float* Wt  = W + (size_t)iw * 512 + (lane << 2);
    const float* apc = ap_buf + apbase + (size_t)iw * 32 + cl;

#pragma unroll 6
    for (int t = 0; t < 24; ++t) {
        const int il = wave * 24 + t;
        const float4 wva = *(const float4*)(Wt + (size_t)t * 512);
        const float4 wvb = *(const float4*)(Wt + (size_t)t * 512 + 256);
        float Ra, Rb;
        if (IT == 0) {
            Ra = 1.0f / 32.0f; Rb = 1.0f / 32.0f;
        } else {
            const float inv = invd_lds[il];
            Ra = fmaf(apc[(size_t)t * 32],      inv, EPS);
            Rb = fmaf(apc[(size_t)t * 32 + 16], inv, EPS);
        }
        const float a_in = act_lds[il];
        const float R4a = Ra * a_in, R4b = Rb * a_in;
        sRa += R4a; sRb += R4b;

        const float4 q0 = *(const float4*)&Pt_lds[il * 16 + 0];
        const float4 q1 = *(const float4*)&Pt_lds[il * 16 + 4];
        const float4 q2 = *(const float4*)&Pt_lds[il * 16 + 8];
        const float4 q3 = *(const float4*)&Pt_lds[il * 16 + 12];

        f32x2 va01, va23, vb01, vb23;
        dot_pairs(wva, q0, q1, q2, q3, va01, va23);
        dot_pairs(wvb, q0, q1, q2, q3, vb01, vb23);

        const f32x2 ra2 = sp2(R4a), rb2 = sp2(R4b);
        s1a01 = fma2(ra2, va01, s1a01);
        s1a23 = fma2(ra2, va23, s1a23);
        s1b01 = fma2(rb2, vb01, s1b01);
        s1b23 = fma2(rb2, vb23, s1b23);
        const f32x2 ua01 = ra2 * va01, ua23 = ra2 * va23;
        const f32x2 ub01 = rb2 * vb01, ub23 = rb2 * vb23;
        s2a01 = fma2(ua01, va01, s2a01);
        s2a23 = fma2(ua23, va23, s2a23);
        s2b01 = fma2(ub01, vb01, s2b01);
        s2b23 = fma2(ub23, vb23, s2b23);
    }

    float acc[18] = {
        s1a01.x, s1a01.y, s1a23.x, s1a23.y,
        s2a01.x, s2a01.y, s2a23.x, s2a23.y,
        s1b01.x, s1b01.y, s1b23.x, s1b23.y,
        s2b01.x, s2b01.y, s2b23.x, s2b23.y,
        sRa, sRb
    };

    if (wave > 0) {
        float* d = &red[((wave - 1) * 64 + lane) * 18];
#pragma unroll
        for (int k = 0; k < 18; ++k) d[k] = acc[k];
    }
    __syncthreads();
    if (wave == 0) {
        float* mp = Mpart + (size_t)bid * 1152;
        const float* r0 = &red[lane * 18];
        const float* r1 = &red[(64 + lane) * 18];
#pragma unroll
        for (int k = 0; k < 18; ++k)
            mp[k * 64 + lane] = acc[k] + r0[k] + r1[k];
    }
}

__global__ __launch_bounds__(192)
void e_pass(const float* __restrict__ Ptg, const float* __restrict__ Mpart,
            const float* __restrict__ W, const float* __restrict__ beta_v,
            const float* __restrict__ beta_a, const float* __restrict__ lambda_p,
            float* __restrict__ ap_buf, float* __restrict__ denom_next)
{
    __shared__ __align__(16) float Pt_lds[1152];
    __shared__ __align__(16) float ap_lds[2304];

    const int tid  = threadIdx.x;
    const int wave = tid / 64, lane = tid & 63;
    const int cl   = lane >> 2, hr = lane & 3;
    const int bid  = blockIdx.x;
    const int blk  = bid >> 2, iq = bid & 3;
    const int bb   = blk / 36;
    const int i0   = iq * 72;
    const int iw   = i0 + wave * 24;
    const size_t pbase  = (size_t)blk * 4608;
    const size_t apbase = (size_t)blk * 9216;

    {
        const float4* src = (const float4*)(Ptg + pbase + (size_t)i0 * 16);
        float4* dst = (float4*)Pt_lds;
        for (int e = tid; e < 288; e += 192) dst[e] = src[e];
    }

    // ---- stats in registers; Horner coeffs packed as hc-pairs ----
    f32x2 cA2a[2], cA1a[2], cA0a[2], cA2b[2], cA1b[2], cA0b[2];
    float aca, acb;
    {
        const float* mp = Mpart + (size_t)blk * 4608;
        float s[18];
#pragma unroll
        for (int k = 0; k < 18; ++k)
            s[k] = mp[k * 64 + lane] + mp[1152 + k * 64 + lane]
                 + mp[2304 + k * 64 + lane] + mp[3456 + k * 64 + lane];
        const float lam = lambda_p[0];
        float A2s[8], A1s[8], A0s[8];
#pragma unroll
        for (int q = 0; q < 2; ++q) {
            const int c = cl + q * 16;
            const float sR = s[16 + q];
            float ls = 0.f;
#pragma unroll
            for (int hc = 0; hc < 4; ++hc) {
                const float mu = s[q * 8 + hc] / sR;
                float ss = s[q * 8 + 4 + hc] / sR - mu * mu;
                ss = fmaxf(ss, 1e-30f);
                const float n2 = (-0.5f / ss) * LOG2E;
                const float hl = (-0.5f * __logf(ss) - HALF_LN2PI) * LOG2E;
                A2s[q * 4 + hc] = n2;
                A1s[q * 4 + hc] = -2.0f * n2 * mu;
                A0s[q * 4 + hc] = fmaf(n2 * mu, mu, hl);
                ls += __logf(sqrtf(ss) + EPS);
            }
            ls += __shfl_xor(ls, 1);
            ls += __shfl_xor(ls, 2);
            const float cost = sR * (16.0f * beta_v[c] + ls);
            const float av = 1.0f / (1.0f + __expf(-lam * (beta_a[c] - cost)));
            if (q) acb = av; else aca = av;
        }
        cA2a[0] = f32x2{A2s[0], A2s[1]}; cA2a[1] = f32x2{A2s[2], A2s[3]};
        cA1a[0] = f32x2{A1s[0], A1s[1]}; cA1a[1] = f32x2{A1s[2], A1s[3]};
        cA0a[0] = f32x2{A0s[0], A0s[1]}; cA0a[1] = f32x2{A0s[2], A0s[3]};
        cA2b[0] = f32x2{A2s[4], A2s[5]}; cA2b[1] = f32x2{A2s[6], A2s[7]};
        cA1b[0] = f32x2{A1s[4], A1s[5]}; cA1b[1] = f32x2{A1s[6], A1s[7]};
        cA0b[0] = f32x2{A0s[4], A0s[5]}; cA0b[1] = f32x2{A0s[6], A0s[7]};
    }
    __syncthreads();

    const float* Wt = W + (size_t)iw * 512 + (lane << 2);

    // ---- t-loop: packed dots + packed Horner + builtin exp2; unroll 8 (r20) ----
#pragma unroll 8
    for (int t = 0; t < 24; ++t) {
        const int il = wave * 24 + t;
        const float4 wva = *(const float4*)(Wt + (size_t)t * 512);
        const float4 wvb = *(const float4*)(Wt + (size_t)t * 512 + 256);

        const float4 q0 = *(const float4*)&Pt_lds[il * 16 + 0];
        const float4 q1 = *(const float4*)&Pt_lds[il * 16 + 4];
        const float4 q2 = *(const float4*)&Pt_lds[il * 16 + 8];
        const float4 q3 = *(const float4*)&Pt_lds[il * 16 + 12];

        f32x2 va01, va23, vb01, vb23;
        dot_pairs(wva, q0, q1, q2, q3, va01, va23);
        dot_pairs(wvb, q0, q1, q2, q3, vb01, vb23);

        const f32x2 ga01 = fma2(va01, fma2(va01, cA2a[0], cA1a[0]), cA0a[0]);
        const f32x2 ga23 = fma2(va23, fma2(va23, cA2a[1], cA1a[1]), cA0a[1]);
        const f32x2 gb01 = fma2(vb01, fma2(vb01, cA2b[0], cA1b[0]), cA0b[0]);
        const f32x2 gb23 = fma2(vb23, fma2(vb23, cA2b[1], cA1b[1]), cA0b[1]);

        float pea = __builtin_amdgcn_exp2f(ga01.x) + __builtin_amdgcn_exp2f(ga01.y)
                  + __builtin_amdgcn_exp2f(ga23.x) + __builtin_amdgcn_exp2f(ga23.y);
        float peb = __builtin_amdgcn_exp2f(gb01.x) + __builtin_amdgcn_exp2f(gb01.y)
                  + __builtin_amdgcn_exp2f(gb23.x) + __builtin_amdgcn_exp2f(gb23.y);

        pea = qxor1_add(pea); pea = qxor2_add(pea);
        peb = qxor1_add(peb); peb = qxor2_add(peb);
        if (hr == 0) {
            ap_lds[il * 32 + cl]      = aca * pea;
            ap_lds[il * 32 + cl + 16] = acb * peb;
        }
    }
    __syncthreads();

    {
        const float4* s4 = (const float4*)ap_lds;
        float4* d4 = (float4*)(ap_buf + apbase + (size_t)i0 * 32);
        for (int e = tid; e < 576; e += 192) d4[e] = s4[e];
    }
    if (tid < 72) {
        float s = 0.f;
#pragma unroll
        for (int c = 0; c < 32; ++c)
            s += ap_lds[tid * 32 + ((c + tid) & 31)];
        atomicAdd(&denom_next[bb * 288 + i0 + tid], s);
    }
}

__global__ __launch_bounds__(64)
void out_pass(const float* __restrict__ Mpart, const float* __restrict__ beta_v,
              const float* __restrict__ beta_a, const float* __restrict__ lambda_p,
              float* __restrict__ d_out)
{
    const int lane = threadIdx.x;
    const int cl = lane >> 2, hr = lane & 3;
    const int blk = blockIdx.x;
    const int bb = blk / 36, p = blk - bb * 36;
    const float* mp = Mpart + (size_t)blk * 4608;

    float s[18];
#pragma unroll
    for (int k = 0; k < 18; ++k)
        s[k] = mp[k * 64 + lane] + mp[1152 + k * 64 + lane]
             + mp[2304 + k * 64 + lane] + mp[3456 + k * 64 + lane];

    const float lam = lambda_p[0];
#pragma unroll
    for (int q = 0; q < 2; ++q) {
        const int c = cl + q * 16;
        const float sR = s[16 + q];
        float ls = 0.f;
#pragma unroll
        for (int hc = 0; hc < 4; ++hc) {
            const float mu = s[q * 8 + hc] / sR;
            float ss = s[q * 8 + 4 + hc] / sR - mu * mu;
            ss = fmaxf(ss, 1e-30f);
            d_out[(size_t)bb * 18432 + (size_t)(c * 36 + p) * 16 + hr * 4 + hc] = mu;
            ls += __logf(sqrtf(ss) + EPS);
        }
        ls += __shfl_xor(ls, 1);
        ls += __shfl_xor(ls, 2);
        const float cost = sR * (16.0f * beta_v[c] + ls);
        const float av = 1.0f / (1.0f + __expf(-lam * (beta_a[c] - cost)));
        if (hr == 0)
            d_out[294912 + (size_t)bb * 1152 + c * 36 + p] = av;
    }
}

extern "C" void kernel_launch(void* const* d_in, const int* in_sizes, int n_in,
                              void* d_out, int out_size, void* d_ws, size_t ws_size,
                              hipStream_t stream)
{
    const float* lambda_p = (const float*)d_in[0];
    const float* poses    = (const float*)d_in[1];
    const float* acts     = (const float*)d_in[2];
    const float* W        = (const float*)d_in[3];
    const float* beta_v   = (const float*)d_in[4];
    const float* beta_a   = (const float*)d_in[5];
    float* out = (float*)d_out;

    float* ws     = (float*)d_ws;
    float* Ptg    = ws;                     // 576*4608 = 2,654,208 floats
    float* actp   = Ptg + 2654208;          // 576*288  =   165,888
    float* ap_buf = actp + 165888;          // 576*9216 = 5,308,416
    float* Mpart  = ap_buf + 5308416;       // 2304*1152 = 2,654,208
    float* denom0 = Mpart + 2654208;        // 4608
    float* denom1 = denom0 + 4608;          // 4608

    m_pass<0><<<2304, 192, 0, stream>>>(poses, acts, Ptg, actp, W, ap_buf, denom1, Mpart, denom0);
    e_pass<<<2304, 192, 0, stream>>>(Ptg, Mpart, W, beta_v, beta_a, lambda_p, ap_buf, denom0);
    m_pass<1><<<2304, 192, 0, stream>>>(poses, acts, Ptg, actp, W, ap_buf, denom0, Mpart, denom1);
    e_pass<<<2304, 192, 0, stream>>>(Ptg, Mpart, W, beta_v, beta_a, lambda_p, ap_buf, denom1);
    m_pass<1><<<2304, 192, 0, stream>>>(poses, acts, Ptg, actp, W, ap_buf, denom1, Mpart, denom0);
    out_pass<<<576, 64, 0, stream>>>(Mpart, beta_v, beta_a, lambda_p, out);
}

// Round 22
// 156.003 us; speedup vs baseline: 1.2095x; 1.0454x over previous
//
#include <hip/hip_runtime.h>

#define EPS 1e-10f
#define HALF_LN2PI 0.91893853320467274f
#define LOG2E 1.4426950408889634f

// b=16, win=14, w=6, ww=36, B_T=32, K=3, Bkk=288 (=i), C_T=32, HH=16
// W flat: [i=288][c=32][hr=4][m=4]
// Pt per (bb,p) (natural layout): Pt[i*16 + e] = patchflat[base(p)+e],
//   e = m*4+hc, base(p)=(p/6)*96+(p%6)*16.
//
// Grid (m/e): 2304 blocks = (blk = bb*36+p)*4 + iq, 192 threads = 3 waves.
// Wave handles 24 i. 9 blocks/CU x 3 waves = 27 waves/CU. VGPR <=64.
// lane = cl*4+hr; thread covers c in {cl, cl+16}, 4 hc each.
// Mpart[bid][k*64+lane], k: [0..3]=S1a [4..7]=S2a [8..11]=S1b [12..15]=S2b [16]=sRa [17]=sRb
//
// Stats hoist (r22, corrected r21): f_pass reduces the 4 iq partials and
// writes PACKED PER-LANE coefficients IN PLACE over Mpart[blk*4608 + ...]:
//   A2 at [q*256 + lane*4 + hc], A1 at +512, A0 at +1024, a at [1536 + q*16 + cl]
// (per-lane keeps the hr dimension — r21 wrote only hr==0's coeffs and
// broadcast them, corrupting rows h>=4; absmax 2.9e-2). Single-wave f_pass +
// vmcnt(0) fence = r9/r10's validated read-then-overwrite pattern.
//
// Structure: m0 -> f0 -> e0 -> m1 -> f1 -> e1 -> m2 -> f<FINAL> (8 dispatches).
//
// Post-mortems: r6 coop grid.sync; r7 full-unroll spill; r8 no global VMEM in
// t-loops; r9 DPP reduce, no memset; r10 stats hoist ok at 2-wave; r11/r12
// output path FREE; r13 preamble ~13-17us by subtraction; r14/r15 null;
// r16 3 waves +7us; r17/r18 packed FP32: VALUBusy -16pt, time flat;
// r19 poly-exp HURT; r20 unroll null; r21 hr-bug.

typedef float f32x2 __attribute__((ext_vector_type(2)));

__device__ __forceinline__ f32x2 fma2(f32x2 a, f32x2 b, f32x2 c) {
    return __builtin_elementwise_fma(a, b, c);
}
__device__ __forceinline__ f32x2 sp2(float x) { return f32x2{x, x}; }

__device__ __forceinline__ void dot_pairs(const float4 wv,
                                          const float4 q0, const float4 q1,
                                          const float4 q2, const float4 q3,
                                          f32x2& out01, f32x2& out23)
{
    out01 = fma2(sp2(wv.x), f32x2{q0.x, q0.y},
            fma2(sp2(wv.y), f32x2{q1.x, q1.y},
            fma2(sp2(wv.z), f32x2{q2.x, q2.y}, sp2(wv.w) * f32x2{q3.x, q3.y})));
    out23 = fma2(sp2(wv.x), f32x2{q0.z, q0.w},
            fma2(sp2(wv.y), f32x2{q1.z, q1.w},
            fma2(sp2(wv.z), f32x2{q2.z, q2.w}, sp2(wv.w) * f32x2{q3.z, q3.w})));
}

__device__ __forceinline__ float qxor1_add(float x) {
    float r;
    asm("v_add_f32 %0, %1, %1 quad_perm:[1,0,3,2] row_mask:0xf bank_mask:0xf"
        : "=v"(r) : "v"(x));
    return r;
}
__device__ __forceinline__ float qxor2_add(float x) {
    float r;
    asm("v_add_f32 %0, %1, %1 quad_perm:[2,3,0,1] row_mask:0xf bank_mask:0xf"
        : "=v"(r) : "v"(x));
    return r;
}

template <int IT>
__global__ __launch_bounds__(192)
void m_pass(const float* __restrict__ poses, const float* __restrict__ acts,
            float* __restrict__ Ptg, float* __restrict__ actp,
            const float* __restrict__ W,
            const float* __restrict__ ap_buf, const float* __restrict__ denom_prev,
            float* __restrict__ Mpart, float* __restrict__ denom_zero)
{
    __shared__ __align__(16) float Pt_lds[1152];
    __shared__ float act_lds[72];
    __shared__ float invd_lds[72];
    __shared__ __align__(16) float red[2304];

    const int tid  = threadIdx.x;
    const int wave = tid / 64, lane = tid & 63;
    const int cl   = lane >> 2;
    const int bid  = blockIdx.x;
    const int blk  = bid >> 2, iq = bid & 3;
    const int bb   = blk / 36, p = blk - bb * 36;
    const int i0   = iq * 72;
    const int iw   = i0 + wave * 24;
    const size_t pbase  = (size_t)blk * 4608;
    const size_t apbase = (size_t)blk * 9216;

    if (tid < 72)
        denom_zero[bb * 288 + i0 + tid] = 0.0f;

    if (IT == 0) {
        const int base = (p / 6) * 96 + (p % 6) * 16;
        for (int e = tid; e < 1152; e += 192) {
            int il = e >> 4, j = e & 15;
            int i = i0 + il;
            int f = base + j;
            int h = f / 36, sp = f - h * 36;
            int y = sp / 6, x = sp - y * 6;
            int B = i / 9, kk = i - B * 9;
            int ki = kk / 3, kj = kk - ki * 3;
            float v = poses[(size_t)((bb * 512 + h * 32 + B) * 14 + 2 * x + ki) * 14 + 2 * y + kj];
            Pt_lds[e] = v;
            Ptg[pbase + (size_t)i0 * 16 + e] = v;
        }
        const int y = p / 6, x = p - y * 6;
        for (int e = tid; e < 72; e += 192) {
            int i = i0 + e;
            int B = i / 9, kk = i - B * 9;
            int ki = kk / 3, kj = kk - ki * 3;
            float v = acts[(size_t)((bb * 32 + B) * 14 + 2 * x + ki) * 14 + 2 * y + kj];
            act_lds[e] = v;
            actp[blk * 288 + i] = v;
        }
    } else {
        const float4* src = (const float4*)(Ptg + pbase + (size_t)i0 * 16);
        float4* dst = (float4*)Pt_lds;
        for (int e = tid; e < 288; e += 192) dst[e] = src[e];
        for (int e = tid; e < 72; e += 192) {
            act_lds[e]  = actp[blk * 288 + i0 + e];
            invd_lds[e] = 1.0f / (denom_prev[bb * 288 + i0 + e] + EPS);
        }
    }
    __syncthreads();

    f32x2 s1a01 = {0,0}, s1a23 = {0,0}, s2a01 = {0,0}, s2a23 = {0,0};
    f32x2 s1b01 = {0,0}, s1b23 = {0,0}, s2b01 = {0,0}, s2b23 = {0,0};
    float sRa = 0.f, sRb = 0.f;

    const float* Wt  = W + (size_t)iw * 512 + (lane << 2);
    const float* apc = ap_buf + apbase + (size_t)iw * 32 + cl;

#pragma unroll 6
    for (int t = 0; t < 24; ++t) {
        const int il = wave * 24 + t;
        const float4 wva = *(const float4*)(Wt + (size_t)t * 512);
        const float4 wvb = *(const float4*)(Wt + (size_t)t * 512 + 256);
        float Ra, Rb;
        if (IT == 0) {
            Ra = 1.0f / 32.0f; Rb = 1.0f / 32.0f;
        } else {
            const float inv = invd_lds[il];
            Ra = fmaf(apc[(size_t)t * 32],      inv, EPS);
            Rb = fmaf(apc[(size_t)t * 32 + 16], inv, EPS);
        }
        const float a_in = act_lds[il];
        const float R4a = Ra * a_in, R4b = Rb * a_in;
        sRa += R4a; sRb += R4b;

        const float4 q0 = *(const float4*)&Pt_lds[il * 16 + 0];
        const float4 q1 = *(const float4*)&Pt_lds[il * 16 + 4];
        const float4 q2 = *(const float4*)&Pt_lds[il * 16 + 8];
        const float4 q3 = *(const float4*)&Pt_lds[il * 16 + 12];

        f32x2 va01, va23, vb01, vb23;
        dot_pairs(wva, q0, q1, q2, q3, va01, va23);
        dot_pairs(wvb, q0, q1, q2, q3, vb01, vb23);

        const f32x2 ra2 = sp2(R4a), rb2 = sp2(R4b);
        s1a01 = fma2(ra2, va01, s1a01);
        s1a23 = fma2(ra2, va23, s1a23);
        s1b01 = fma2(rb2, vb01, s1b01);
        s1b23 = fma2(rb2, vb23, s1b23);
        const f32x2 ua01 = ra2 * va01, ua23 = ra2 * va23;
        const f32x2 ub01 = rb2 * vb01, ub23 = rb2 * vb23;
        s2a01 = fma2(ua01, va01, s2a01);
        s2a23 = fma2(ua23, va23, s2a23);
        s2b01 = fma2(ub01, vb01, s2b01);
        s2b23 = fma2(ub23, vb23, s2b23);
    }

    float acc[18] = {
        s1a01.x, s1a01.y, s1a23.x, s1a23.y,
        s2a01.x, s2a01.y, s2a23.x, s2a23.y,
        s1b01.x, s1b01.y, s1b23.x, s1b23.y,
        s2b01.x, s2b01.y, s2b23.x, s2b23.y,
        sRa, sRb
    };

    if (wave > 0) {
        float* d = &red[((wave - 1) * 64 + lane) * 18];
#pragma unroll
        for (int k = 0; k < 18; ++k) d[k] = acc[k];
    }
    __syncthreads();
    if (wave == 0) {
        float* mp = Mpart + (size_t)bid * 1152;
        const float* r0 = &red[lane * 18];
        const float* r1 = &red[(64 + lane) * 18];
#pragma unroll
        for (int k = 0; k < 18; ++k)
            mp[k * 64 + lane] = acc[k] + r0[k] + r1[k];
    }
}

// f_pass: reduce Mpart's 4 iq partials; FINAL=0: write packed PER-LANE
// Horner coefficients in place over Mpart[blk]; FINAL=1: write d_out.
template <int FINAL>
__global__ __launch_bounds__(64)
void f_pass(float* __restrict__ Mpart, const float* __restrict__ beta_v,
            const float* __restrict__ beta_a, const float* __restrict__ lambda_p,
            float* __restrict__ d_out)
{
    const int lane = threadIdx.x;
    const int cl = lane >> 2, hr = lane & 3;
    const int blk = blockIdx.x;
    const int bb = blk / 36, p = blk - bb * 36;
    float* mp = Mpart + (size_t)blk * 4608;

    float s[18];
#pragma unroll
    for (int k = 0; k < 18; ++k)
        s[k] = mp[k * 64 + lane] + mp[1152 + k * 64 + lane]
             + mp[2304 + k * 64 + lane] + mp[3456 + k * 64 + lane];

    const float lam = lambda_p[0];
    float A2s[8], A1s[8], A0s[8], muv[8], av[2];
#pragma unroll
    for (int q = 0; q < 2; ++q) {
        const int c = cl + q * 16;
        const float sR = s[16 + q];
        float ls = 0.f;
#pragma unroll
        for (int hc = 0; hc < 4; ++hc) {
            const float mu = s[q * 8 + hc] / sR;
            float ss = s[q * 8 + 4 + hc] / sR - mu * mu;
            ss = fmaxf(ss, 1e-30f);
            const float n2 = (-0.5f / ss) * LOG2E;
            const float hl = (-0.5f * __logf(ss) - HALF_LN2PI) * LOG2E;
            muv[q * 4 + hc] = mu;
            A2s[q * 4 + hc] = n2;
            A1s[q * 4 + hc] = -2.0f * n2 * mu;
            A0s[q * 4 + hc] = fmaf(n2 * mu, mu, hl);
            ls += __logf(sqrtf(ss) + EPS);
        }
        ls += __shfl_xor(ls, 1);
        ls += __shfl_xor(ls, 2);
        const float cost = sR * (16.0f * beta_v[c] + ls);
        av[q] = 1.0f / (1.0f + __expf(-lam * (beta_a[c] - cost)));
    }

    if (FINAL) {
#pragma unroll
        for (int q = 0; q < 2; ++q) {
            const int c = cl + q * 16;
#pragma unroll
            for (int hc = 0; hc < 4; ++hc)
                d_out[(size_t)bb * 18432 + (size_t)(c * 36 + p) * 16 + hr * 4 + hc] = muv[q * 4 + hc];
            if (hr == 0)
                d_out[294912 + (size_t)bb * 1152 + c * 36 + p] = av[q];
        }
    } else {
        // in-place overwrite of Mpart[blk]; single wave + fence orders all
        // reads before any store (r9/r10-validated pattern).
        asm volatile("s_waitcnt vmcnt(0)" ::: "memory");
#pragma unroll
        for (int q = 0; q < 2; ++q) {
#pragma unroll
            for (int hc = 0; hc < 4; ++hc) {
                const int ix = q * 256 + lane * 4 + hc;
                mp[ix]        = A2s[q * 4 + hc];
                mp[512 + ix]  = A1s[q * 4 + hc];
                mp[1024 + ix] = A0s[q * 4 + hc];
            }
            if (hr == 0) mp[1536 + q * 16 + cl] = av[q];
        }
    }
}

__global__ __launch_bounds__(192)
void e_pass(const float* __restrict__ Ptg, const float* __restrict__ Mpart,
            const float* __restrict__ W,
            float* __restrict__ ap_buf, float* __restrict__ denom_next)
{
    __shared__ __align__(16) float Pt_lds[1152];
    __shared__ __align__(16) float ap_lds[2304];

    const int tid  = threadIdx.x;
    const int wave = tid / 64, lane = tid & 63;
    const int cl   = lane >> 2, hr = lane & 3;
    const int bid  = blockIdx.x;
    const int blk  = bid >> 2, iq = bid & 3;
    const int bb   = blk / 36;
    const int i0   = iq * 72;
    const int iw   = i0 + wave * 24;
    const size_t pbase  = (size_t)blk * 4608;
    const size_t apbase = (size_t)blk * 9216;

    {
        const float4* src = (const float4*)(Ptg + pbase + (size_t)i0 * 16);
        float4* dst = (float4*)Pt_lds;
        for (int e = tid; e < 288; e += 192) dst[e] = src[e];
    }

    // preamble: 6 float4 + 2 scalar loads of PER-LANE coefficients (r22)
    const float* st = Mpart + (size_t)blk * 4608;
    const float4 a2 = *(const float4*)&st[lane * 4];
    const float4 b2 = *(const float4*)&st[256 + lane * 4];
    const float4 a1 = *(const float4*)&st[512 + lane * 4];
    const float4 b1 = *(const float4*)&st[768 + lane * 4];
    const float4 a0 = *(const float4*)&st[1024 + lane * 4];
    const float4 b0 = *(const float4*)&st[1280 + lane * 4];
    const float aca = st[1536 + cl];
    const float acb = st[1552 + cl];

    f32x2 cA2a[2] = {f32x2{a2.x, a2.y}, f32x2{a2.z, a2.w}};
    f32x2 cA1a[2] = {f32x2{a1.x, a1.y}, f32x2{a1.z, a1.w}};
    f32x2 cA0a[2] = {f32x2{a0.x, a0.y}, f32x2{a0.z, a0.w}};
    f32x2 cA2b[2] = {f32x2{b2.x, b2.y}, f32x2{b2.z, b2.w}};
    f32x2 cA1b[2] = {f32x2{b1.x, b1.y}, f32x2{b1.z, b1.w}};
    f32x2 cA0b[2] = {f32x2{b0.x, b0.y}, f32x2{b0.z, b0.w}};
    __syncthreads();

    const float* Wt = W + (size_t)iw * 512 + (lane << 2);

#pragma unroll 8
    for (int t = 0; t < 24; ++t) {
        const int il = wave * 24 + t;
        const float4 wva = *(const float4*)(Wt + (size_t)t * 512);
        const float4 wvb = *(const float4*)(Wt + (size_t)t * 512 + 256);

        const float4 q0 = *(const float4*)&Pt_lds[il * 16 + 0];
        const float4 q1 = *(const float4*)&Pt_lds[il * 16 + 4];
        const float4 q2 = *(const float4*)&Pt_lds[il * 16 + 8];
        const float4 q3 = *(const float4*)&Pt_lds[il * 16 + 12];

        f32x2 va01, va23, vb01, vb23;
        dot_pairs(wva, q0, q1, q2, q3, va01, va23);
        dot_pairs(wvb, q0, q1, q2, q3, vb01, vb23);

        const f32x2 ga01 = fma2(va01, fma2(va01, cA2a[0], cA1a[0]), cA0a[0]);
        const f32x2 ga23 = fma2(va23, fma2(va23, cA2a[1], cA1a[1]), cA0a[1]);
        const f32x2 gb01 = fma2(vb01, fma2(vb01, cA2b[0], cA1b[0]), cA0b[0]);
        const f32x2 gb23 = fma2(vb23, fma2(vb23, cA2b[1], cA1b[1]), cA0b[1]);

        float pea = __builtin_amdgcn_exp2f(ga01.x) + __builtin_amdgcn_exp2f(ga01.y)
                  + __builtin_amdgcn_exp2f(ga23.x) + __builtin_amdgcn_exp2f(ga23.y);
        float peb = __builtin_amdgcn_exp2f(gb01.x) + __builtin_amdgcn_exp2f(gb01.y)
                  + __builtin_amdgcn_exp2f(gb23.x) + __builtin_amdgcn_exp2f(gb23.y);

        pea = qxor1_add(pea); pea = qxor2_add(pea);
        peb = qxor1_add(peb); peb = qxor2_add(peb);
        if (hr == 0) {
            ap_lds[il * 32 + cl]      = aca * pea;
            ap_lds[il * 32 + cl + 16] = acb * peb;
        }
    }
    __syncthreads();

    {
        const float4* s4 = (const float4*)ap_lds;
        float4* d4 = (float4*)(ap_buf + apbase + (size_t)i0 * 32);
        for (int e = tid; e < 576; e += 192) d4[e] = s4[e];
    }
    if (tid < 72) {
        float s = 0.f;
#pragma unroll
        for (int c = 0; c < 32; ++c)
            s += ap_lds[tid * 32 + ((c + tid) & 31)];
        atomicAdd(&denom_next[bb * 288 + i0 + tid], s);
    }
}

extern "C" void kernel_launch(void* const* d_in, const int* in_sizes, int n_in,
                              void* d_out, int out_size, void* d_ws, size_t ws_size,
                              hipStream_t stream)
{
    const float* lambda_p = (const float*)d_in[0];
    const float* poses    = (const float*)d_in[1];
    const float* acts     = (const float*)d_in[2];
    const float* W        = (const float*)d_in[3];
    const float* beta_v   = (const float*)d_in[4];
    const float* beta_a   = (const float*)d_in[5];
    float* out = (float*)d_out;

    float* ws     = (float*)d_ws;
    float* Ptg    = ws;                     // 2,654,208 floats
    float* actp   = Ptg + 2654208;          //   165,888
    float* ap_buf = actp + 165888;          // 5,308,416
    float* Mpart  = ap_buf + 5308416;       // 2,654,208 (moments, then coeffs in place)
    float* denom0 = Mpart + 2654208;        // 4608
    float* denom1 = denom0 + 4608;          // 4608

    m_pass<0><<<2304, 192, 0, stream>>>(poses, acts, Ptg, actp, W, ap_buf, denom1, Mpart, denom0);
    f_pass<0><<<576, 64, 0, stream>>>(Mpart, beta_v, beta_a, lambda_p, out);
    e_pass<<<2304, 192, 0, stream>>>(Ptg, Mpart, W, ap_buf, denom0);
    m_pass<1><<<2304, 192, 0, stream>>>(poses, acts, Ptg, actp, W, ap_buf, denom0, Mpart, denom1);
    f_pass<0><<<576, 64, 0, stream>>>(Mpart, beta_v, beta_a, lambda_p, out);
    e_pass<<<2304, 192, 0, stream>>>(Ptg, Mpart, W, ap_buf, denom1);
    m_pass<1><<<2304, 192, 0, stream>>>(poses, acts, Ptg, actp, W, ap_buf, denom1, Mpart, denom0);
    f_pass<1><<<576, 64, 0, stream>>>(Mpart, beta_v, beta_a, lambda_p, out);
}